// Round 4
// baseline (936.220 us; speedup 1.0000x reference)
//
#include <hip/hip_runtime.h>
#include <stdint.h>

// No implicit FMA contraction: the JAX eager reference has none across ops;
// where XLA fuses we write fmaf() explicitly.
#pragma clang fp contract(off)

#define PDIM 162
#define ROWS (2*PDIM*PDIM)      // 52488 rows (n,z,y)
#define WPR  3                  // 64-bit words per row
#define NW   (ROWS*WPR)         // 157464 words, 1.26 MB per bitboard
#define OD   160
#define OD2  (160*160)
#define OD3  (160*160*160)
#define NOUT (2*OD3)

#define NE_T (2u*160u*160u*3u)  // endpoint word-tasks
#define NS_T (2u*80u*80u*3u)    // subfield word-tasks
#define GBLK 256
#define GTHR 256
#define GSZ  (GBLK*GTHR)
// barrier memory: 32 leaf counters (32 u32 apart = 128B) + 1 root
#define BAR_WORDS 1056

// ---------------- threefry2x32, JAX partitionable scheme --------------------
__device__ __forceinline__ uint32_t rotl32(uint32_t x, uint32_t r) {
  return (x << r) | (x >> (32u - r));
}

__device__ __forceinline__ uint32_t threefry_bits(uint32_t idx) {
  const uint32_t ks0 = 0u, ks1 = 42u, ks2 = 0x1BD11BDAu ^ 0u ^ 42u;
  uint32_t x0 = 0u + ks0;
  uint32_t x1 = idx + ks1;
#define TFR(r) { x0 += x1; x1 = rotl32(x1, (r)); x1 ^= x0; }
  TFR(13u) TFR(15u) TFR(26u) TFR(6u)
  x0 += ks1; x1 += ks2 + 1u;
  TFR(17u) TFR(29u) TFR(16u) TFR(24u)
  x0 += ks2; x1 += ks0 + 2u;
  TFR(13u) TFR(15u) TFR(26u) TFR(6u)
  x0 += ks0; x1 += ks1 + 3u;
  TFR(17u) TFR(29u) TFR(16u) TFR(24u)
  x0 += ks1; x1 += ks2 + 4u;
  TFR(13u) TFR(15u) TFR(26u) TFR(6u)
  x0 += ks2; x1 += ks0 + 5u;
#undef TFR
  return x0 ^ x1;
}

// ------------- XLA-CPU (Cephes) float32 log replication ---------------------
__device__ __forceinline__ float xla_logf(float xin) {
  uint32_t bits = __float_as_uint(xin);
  float e = (float)((int)(bits >> 23) - 126);
  float x = __uint_as_float((bits & 0x007fffffu) | 0x3f000000u);
  const float SQRTHF = 0.707106781186547524f;
  bool lt = (x < SQRTHF);
  float tmp = lt ? x : 0.0f;
  e = e - (lt ? 1.0f : 0.0f);
  x = x - 1.0f;
  x = x + tmp;
  float z = x * x;
  float y = 7.0376836292e-2f;
  y = fmaf(y, x, -1.1514610310e-1f);
  y = fmaf(y, x,  1.1676998740e-1f);
  y = fmaf(y, x, -1.2420140846e-1f);
  y = fmaf(y, x,  1.4249322787e-1f);
  y = fmaf(y, x, -1.6668057665e-1f);
  y = fmaf(y, x,  2.0000714765e-1f);
  y = fmaf(y, x, -2.4999993993e-1f);
  y = fmaf(y, x,  3.3333331174e-1f);
  y = y * x;
  y = y * z;
  y = fmaf(e, -2.12194440e-4f, y);
  y = fmaf(-0.5f, z, y);
  x = x + y;
  x = fmaf(e, 0.693359375f, x);
  return x;
}

__device__ __forceinline__ float xla_log1pf(float x) {
  float for_large = xla_logf(x + 1.0f);
  float for_small = fmaf(-0.5f, x, 1.0f) * x;
  return (fabsf(x) < 1e-4f) ? for_small : for_large;
}

// ---------------------------- binarize --------------------------------------
// One wave computes 64 voxel decisions, packs via ballot. Block 0 also
// zero-inits the grid-barrier memory (re-done every replay; ws is poisoned).
__global__ __launch_bounds__(256) void k_binarize(const float* __restrict__ in,
                                                  uint64_t* __restrict__ bits,
                                                  uint32_t* __restrict__ bar) {
  if (blockIdx.x == 0) {
    for (uint32_t j = threadIdx.x; j < BAR_WORDS; j += 256u) bar[j] = 0u;
  }
  uint32_t t = blockIdx.x * 256u + threadIdx.x;
  uint32_t w = t >> 6, lane = t & 63u;
  if (w >= (uint32_t)NW) return;          // wave-uniform
  uint32_t row = w / 3u, wx = w - row * 3u;
  uint32_t n  = row / (uint32_t)(PDIM * PDIM);
  uint32_t rr = row - n * (uint32_t)(PDIM * PDIM);
  uint32_t z  = rr / (uint32_t)PDIM;
  uint32_t y  = rr - z * (uint32_t)PDIM;
  uint32_t x  = wx * 64u + lane;
  bool pred = false;
  // pad voxels are provably 0: |0.33*noise| <= 6.08 < 18.42 = |log alpha(0)|
  if ((z - 1u) < 160u && (y - 1u) < 160u && (x - 1u) < 160u) {
    float v = in[((n * 160u + (z - 1u)) * 160u + (y - 1u)) * 160u + (x - 1u)];
    uint32_t i = row * 162u + x;          // flat padded index for RNG
    uint32_t b = threefry_bits(i);
    float f  = __uint_as_float((b >> 9) | 0x3f800000u) - 1.0f;
    float uu = fmaxf(1e-8f, f + 1e-8f);
    float la = xla_logf((v + 1e-8f) / ((1.0f - v) + 1e-8f));
    float noise = xla_logf(uu) - xla_log1pf(-uu);
    float zs = la + noise * 0.33f;
    pred = (zs > 1.1920928955078125e-7f); // logistic>0.5 iff z>2^-23
  }
  uint64_t m = __ballot(pred);
  if (lane == 0) bits[w] = m;
}

// ---------------------------- grid barrier ----------------------------------
// Monotonic two-level barrier: 8 blocks -> leaf (32 leaves, 128B apart),
// leaf-last -> root. All spin on root. No resets -> no reset-order hazards.
__device__ __forceinline__ void grid_barrier(uint32_t* __restrict__ bar,
                                             uint32_t b1 /* barrier #, 1-based */) {
  __syncthreads();                        // drains vmem (compiler emits waitcnt)
  if (threadIdx.x == 0) {
    __builtin_amdgcn_fence(__ATOMIC_SEQ_CST, "agent");   // release: wb L2
    uint32_t* lf = bar + (blockIdx.x & 31u) * 32u;
    uint32_t old = __hip_atomic_fetch_add(lf, 1u, __ATOMIC_ACQ_REL,
                                          __HIP_MEMORY_SCOPE_AGENT);
    if (old == 8u * b1 - 1u) {            // last of this leaf's 8 blocks
      __hip_atomic_fetch_add(bar + 32u * 32u, 1u, __ATOMIC_ACQ_REL,
                             __HIP_MEMORY_SCOPE_AGENT);
    }
    while (__hip_atomic_load(bar + 32u * 32u, __ATOMIC_RELAXED,
                             __HIP_MEMORY_SCOPE_AGENT) < 32u * b1) {
      __builtin_amdgcn_s_sleep(1);
    }
    __builtin_amdgcn_fence(__ATOMIC_SEQ_CST, "agent");   // acquire: inv L1/L2
  }
  __syncthreads();
}

// ---------------------------- phase bodies ----------------------------------
__device__ __forceinline__ void endpoint_task(uint32_t t,
                                              const uint64_t* __restrict__ bits,
                                              uint64_t* __restrict__ ge2) {
  uint32_t r160 = t / 3u, wx = t - r160 * 3u;
  uint32_t n  = r160 / (160u * 160u);
  uint32_t rr = r160 - n * (160u * 160u);
  uint32_t z  = rr / 160u + 1u;
  uint32_t y  = rr - (rr / 160u) * 160u + 1u;
  int row = (int)((n * 162u + z) * 162u + y);
  uint32_t w = (uint32_t)row * 3u + wx;
  if (bits[w] == 0ull) { ge2[w] = 0ull; return; }  // only read ANDed with center
  uint64_t s = 0, c = 0;
#define ACC(bb) { uint64_t _b = (bb); c |= s & _b; s |= _b; }
#pragma unroll
  for (int dz = -1; dz <= 1; ++dz)
#pragma unroll
    for (int dy = -1; dy <= 1; ++dy) {
      uint32_t idx = (uint32_t)(row + dz * 162 + dy) * 3u + wx;
      uint64_t b = bits[idx];
      uint64_t a = (wx > 0u) ? bits[idx - 1u] : 0ull;
      uint64_t d = (wx < 2u) ? bits[idx + 1u] : 0ull;
      ACC((b << 1) | (a >> 63));
      ACC((b >> 1) | (d << 63));
      if (dz != 0 || dy != 0) ACC(b);
    }
#undef ACC
  ge2[w] = c;                             // bit set iff C26 >= 2 (not endpoint)
}

#define NB(dz,dy,dx) ((dx)==-1 ? Lb[(dz)+1][(dy)+1] : ((dx)==1 ? Rb[(dz)+1][(dy)+1] : V[(dz)+1][(dy)+1]))

__device__ __forceinline__ void subfield_task(uint32_t t,
                                              uint64_t* __restrict__ bits,
                                              const uint64_t* __restrict__ ge2,
                                              uint32_t zbase, uint32_t ybase,
                                              uint64_t xmask) {
  uint32_t ri = t / 3u, wx = t - ri * 3u;
  uint32_t n  = ri / (80u * 80u);
  uint32_t rr = ri - n * (80u * 80u);
  uint32_t zi = rr / 80u, yi = rr - zi * 80u;
  uint32_t z = zbase + 2u * zi;
  uint32_t y = ybase + 2u * yi;
  int row = (int)((n * 162u + z) * 162u + y);
  uint32_t w = (uint32_t)row * 3u + wx;
  uint64_t center = bits[w];
  uint64_t active = center & xmask & ge2[w];
  if (active == 0ull) return;

  uint64_t V[3][3], Lb[3][3], Rb[3][3];
#pragma unroll
  for (int dz = -1; dz <= 1; ++dz)
#pragma unroll
    for (int dy = -1; dy <= 1; ++dy) {
      uint32_t idx = (uint32_t)(row + dz * 162 + dy) * 3u + wx;
      uint64_t b = bits[idx];
      uint64_t a = (wx > 0u) ? bits[idx - 1u] : 0ull;
      uint64_t d = (wx < 2u) ? bits[idx + 1u] : 0ull;
      V [dz+1][dy+1] = b;
      Lb[dz+1][dy+1] = (b << 1) | (a >> 63);
      Rb[dz+1][dy+1] = (b >> 1) | (d << 63);
    }

  // C6 exact 3-bit counter over the 6 faces
  uint64_t on = 0, tw = 0, fo = 0;
#define C6ADD(b) { uint64_t _u = on & (b); on ^= (b); uint64_t _v = tw & _u; tw ^= _u; fo |= _v; }
  C6ADD(NB(-1,0,0)) C6ADD(NB(1,0,0)) C6ADD(NB(0,-1,0))
  C6ADD(NB(0,1,0))  C6ADD(NB(0,0,-1)) C6ADD(NB(0,0,1))
#undef C6ADD
  uint64_t c6eq5 = fo & on & ~tw;
  uint64_t c6le4 = ~(fo & (on | tw));

  // carry-save ==1 detectors over 18 then 26 neighbors
  uint64_t s = 0, c2 = 0;
#define CS(b) { uint64_t _b = (b); c2 |= s & _b; s |= _b; }
  CS(NB(-1,0,0)) CS(NB(1,0,0)) CS(NB(0,-1,0)) CS(NB(0,1,0)) CS(NB(0,0,-1)) CS(NB(0,0,1))
  CS(NB(-1,-1,0)) CS(NB(-1,1,0)) CS(NB(-1,0,-1)) CS(NB(-1,0,1))
  CS(NB(1,-1,0))  CS(NB(1,1,0))  CS(NB(1,0,-1))  CS(NB(1,0,1))
  CS(NB(0,-1,-1)) CS(NB(0,-1,1)) CS(NB(0,1,-1))  CS(NB(0,1,1))
  uint64_t e18 = s & ~c2;
  CS(NB(-1,-1,-1)) CS(NB(-1,-1,1)) CS(NB(-1,1,-1)) CS(NB(-1,1,1))
  CS(NB(1,-1,-1))  CS(NB(1,-1,1))  CS(NB(1,1,-1))  CS(NB(1,1,1))
  uint64_t e26 = s & ~c2;
#undef CS

  // B: corner set with its 6 octant face/edge cells all clear
  uint64_t badB = 0;
#pragma unroll
  for (int sz = -1; sz <= 1; sz += 2)
#pragma unroll
    for (int sy = -1; sy <= 1; sy += 2)
#pragma unroll
      for (int sx = -1; sx <= 1; sx += 2) {
        uint64_t oct = NB(sz,0,0) | NB(0,sy,0) | NB(0,0,sx)
                     | NB(sz,sy,0) | NB(sz,0,sx) | NB(0,sy,sx);
        badB |= NB(sz,sy,sx) & ~oct;
      }
  uint64_t b0ok = ~badB;

  // A: face clear with its full 4-cell in-plane ring set
  uint64_t badA = 0;
  badA |= ~NB(-1,0,0) & NB(-1,-1,0) & NB(-1,1,0) & NB(-1,0,-1) & NB(-1,0,1);
  badA |= ~NB( 1,0,0) & NB( 1,-1,0) & NB( 1,1,0) & NB( 1,0,-1) & NB( 1,0,1);
  badA |= ~NB(0,-1,0) & NB(-1,-1,0) & NB(1,-1,0) & NB(0,-1,-1) & NB(0,-1,1);
  badA |= ~NB(0, 1,0) & NB(-1, 1,0) & NB(1, 1,0) & NB(0, 1,-1) & NB(0, 1,1);
  badA |= ~NB(0,0,-1) & NB(-1,0,-1) & NB(1,0,-1) & NB(0,-1,-1) & NB(0,1,-1);
  badA |= ~NB(0,0, 1) & NB(-1,0, 1) & NB(1,0, 1) & NB(0,-1, 1) & NB(0,1, 1);
  uint64_t a0ok = ~badA;

  uint64_t simple = c6eq5 | e26 | (e18 & b0ok) | (c6le4 & a0ok & b0ok);
  uint64_t del = simple & active;
  if (del) bits[w] = center & ~del;
}

__device__ __forceinline__ void output_task(uint32_t t,
                                            const uint64_t* __restrict__ bits,
                                            float4* __restrict__ out) {
  uint32_t i = t * 4u;
  uint32_t n = i / (uint32_t)OD3;
  uint32_t r = i - n * (uint32_t)OD3;
  uint32_t z = r / (uint32_t)OD2; r -= z * (uint32_t)OD2;
  uint32_t y = r / (uint32_t)OD;
  uint32_t x = r - y * (uint32_t)OD;
  uint32_t row = (n * 162u + z + 1u) * 162u + (y + 1u);
  uint32_t bi = x + 1u;
  uint32_t wx = bi >> 6, sft = bi & 63u;
  uint64_t v = bits[row * 3u + wx] >> sft;
  if (sft > 60u) v |= bits[row * 3u + wx + 1u] << (64u - sft);
  out[t] = make_float4((float)(v & 1u), (float)((v >> 1) & 1u),
                       (float)((v >> 2) & 1u), (float)((v >> 3) & 1u));
}

// ---------------------------- persistent kernel -----------------------------
__global__ __launch_bounds__(256) void k_persist(uint64_t* __restrict__ bits,
                                                 uint64_t* __restrict__ ge2,
                                                 uint32_t* __restrict__ bar,
                                                 float4* __restrict__ out) {
  const uint32_t gtid = blockIdx.x * 256u + threadIdx.x;
  // subfield parity tables: (o2,o3,o4) per reference offsets order
  const uint32_t ZB[8] = {2,1,2,1,2,1,2,1};
  const uint32_t YB[8] = {2,2,1,1,2,2,1,1};
  uint32_t bcnt = 0;
  for (int it = 0; it < 5; ++it) {
    for (uint32_t t = gtid; t < NE_T; t += GSZ) endpoint_task(t, bits, ge2);
    grid_barrier(bar, ++bcnt);
    for (int s8 = 0; s8 < 8; ++s8) {
      uint64_t xmask = (s8 < 4) ? 0x5555555555555555ull : 0xAAAAAAAAAAAAAAAAull;
      for (uint32_t t = gtid; t < NS_T; t += GSZ)
        subfield_task(t, bits, ge2, ZB[s8], YB[s8], xmask);
      grid_barrier(bar, ++bcnt);
    }
  }
  for (uint32_t t = gtid; t < (uint32_t)(NOUT / 4); t += GSZ)
    output_task(t, bits, out);
}

// ---------------------------- launcher --------------------------------------
extern "C" void kernel_launch(void* const* d_in, const int* in_sizes, int n_in,
                              void* d_out, int out_size, void* d_ws, size_t ws_size,
                              hipStream_t stream) {
  const float* in = (const float*)d_in[0];
  float4* out = (float4*)d_out;
  uint64_t* bits = (uint64_t*)d_ws;        // NW words
  uint64_t* ge2  = bits + NW;              // NW words
  uint32_t* bar  = (uint32_t*)(ge2 + NW);  // BAR_WORDS u32, zeroed by k_binarize

  dim3 blk(256);
  k_binarize<<<dim3((NW * 64 + 255) / 256), blk, 0, stream>>>(in, bits, bar);
  k_persist<<<dim3(GBLK), blk, 0, stream>>>(bits, ge2, bar, out);
}

// Round 5
// 281.728 us; speedup vs baseline: 3.3231x; 3.3231x over previous
//
#include <hip/hip_runtime.h>
#include <stdint.h>

// No implicit FMA contraction: the JAX eager reference has none across ops;
// where XLA fuses we write fmaf() explicitly.
#pragma clang fp contract(off)

#define PDIM 162
#define WPR  3
#define NW   (2*PDIM*PDIM*WPR)  // 157464 words, 1.26 MB per bitboard
#define OD   160

// ---------------- threefry2x32, JAX partitionable scheme --------------------
__device__ __forceinline__ uint32_t rotl32(uint32_t x, uint32_t r) {
  return (x << r) | (x >> (32u - r));
}

__device__ __forceinline__ uint32_t threefry_bits(uint32_t idx) {
  const uint32_t ks0 = 0u, ks1 = 42u, ks2 = 0x1BD11BDAu ^ 0u ^ 42u;
  uint32_t x0 = 0u + ks0;
  uint32_t x1 = idx + ks1;
#define TFR(r) { x0 += x1; x1 = rotl32(x1, (r)); x1 ^= x0; }
  TFR(13u) TFR(15u) TFR(26u) TFR(6u)
  x0 += ks1; x1 += ks2 + 1u;
  TFR(17u) TFR(29u) TFR(16u) TFR(24u)
  x0 += ks2; x1 += ks0 + 2u;
  TFR(13u) TFR(15u) TFR(26u) TFR(6u)
  x0 += ks0; x1 += ks1 + 3u;
  TFR(17u) TFR(29u) TFR(16u) TFR(24u)
  x0 += ks1; x1 += ks2 + 4u;
  TFR(13u) TFR(15u) TFR(26u) TFR(6u)
  x0 += ks2; x1 += ks0 + 5u;
#undef TFR
  return x0 ^ x1;
}

// ------------- XLA-CPU (Cephes) float32 log replication ---------------------
__device__ __forceinline__ float xla_logf(float xin) {
  uint32_t bits = __float_as_uint(xin);
  float e = (float)((int)(bits >> 23) - 126);
  float x = __uint_as_float((bits & 0x007fffffu) | 0x3f000000u);
  const float SQRTHF = 0.707106781186547524f;
  bool lt = (x < SQRTHF);
  float tmp = lt ? x : 0.0f;
  e = e - (lt ? 1.0f : 0.0f);
  x = x - 1.0f;
  x = x + tmp;
  float z = x * x;
  float y = 7.0376836292e-2f;
  y = fmaf(y, x, -1.1514610310e-1f);
  y = fmaf(y, x,  1.1676998740e-1f);
  y = fmaf(y, x, -1.2420140846e-1f);
  y = fmaf(y, x,  1.4249322787e-1f);
  y = fmaf(y, x, -1.6668057665e-1f);
  y = fmaf(y, x,  2.0000714765e-1f);
  y = fmaf(y, x, -2.4999993993e-1f);
  y = fmaf(y, x,  3.3333331174e-1f);
  y = y * x;
  y = y * z;
  y = fmaf(e, -2.12194440e-4f, y);
  y = fmaf(-0.5f, z, y);
  x = x + y;
  x = fmaf(e, 0.693359375f, x);
  return x;
}

__device__ __forceinline__ float xla_log1pf(float x) {
  float for_large = xla_logf(x + 1.0f);
  float for_small = fmaf(-0.5f, x, 1.0f) * x;
  return (fabsf(x) < 1e-4f) ? for_small : for_large;
}

// ---------------------------- binarize --------------------------------------
// One wave computes 64 voxel decisions, packs via ballot. Writes ALL words
// (pad rows = 0), so bufA's pad region is valid every replay.
__global__ __launch_bounds__(256) void k_binarize(const float* __restrict__ in,
                                                  uint64_t* __restrict__ bits) {
  uint32_t t = blockIdx.x * 256u + threadIdx.x;
  uint32_t w = t >> 6, lane = t & 63u;
  if (w >= (uint32_t)NW) return;          // wave-uniform
  uint32_t row = w / 3u, wx = w - row * 3u;
  uint32_t n  = row / (uint32_t)(PDIM * PDIM);
  uint32_t rr = row - n * (uint32_t)(PDIM * PDIM);
  uint32_t z  = rr / (uint32_t)PDIM;
  uint32_t y  = rr - z * (uint32_t)PDIM;
  uint32_t x  = wx * 64u + lane;
  bool pred = false;
  // pad voxels are provably 0: |0.33*noise| <= 6.08 < 18.42 = |log alpha(0)|
  if ((z - 1u) < 160u && (y - 1u) < 160u && (x - 1u) < 160u) {
    float v = in[((n * 160u + (z - 1u)) * 160u + (y - 1u)) * 160u + (x - 1u)];
    uint32_t i = row * 162u + x;          // flat padded index for RNG
    uint32_t b = threefry_bits(i);
    float f  = __uint_as_float((b >> 9) | 0x3f800000u) - 1.0f;
    float uu = fmaxf(1e-8f, f + 1e-8f);
    float la = xla_logf((v + 1e-8f) / ((1.0f - v) + 1e-8f));
    float noise = xla_logf(uu) - xla_log1pf(-uu);
    float zs = la + noise * 0.33f;
    pred = (zs > 1.1920928955078125e-7f); // logistic>0.5 iff z>2^-23
  }
  uint64_t m = __ballot(pred);
  if (lane == 0) bits[w] = m;
}

// ------------------------ neighborhood gather (LDS) -------------------------
struct Nbhd { uint64_t V[3][3], Lb[3][3], Rb[3][3]; };

__device__ __forceinline__ void gather(const uint64_t* __restrict__ Bt,
                                       int lz, int ly, int w, Nbhd& N) {
#pragma unroll
  for (int dz = -1; dz <= 1; ++dz)
#pragma unroll
    for (int dy = -1; dy <= 1; ++dy) {
      const uint64_t* rp = &Bt[((lz + dz) * 32 + (ly + dy)) * 3];
      uint64_t r0 = rp[0], r1 = rp[1], r2 = rp[2];
      uint64_t b = (w == 0) ? r0 : ((w == 1) ? r1 : r2);
      uint64_t a = (w == 0) ? 0ull : ((w == 1) ? r0 : r1);
      uint64_t d = (w == 0) ? r1 : ((w == 1) ? r2 : 0ull);
      N.V [dz+1][dy+1] = b;
      N.Lb[dz+1][dy+1] = (b << 1) | (a >> 63);
      N.Rb[dz+1][dy+1] = (b >> 1) | (d << 63);
    }
}

#define NB(dz,dy,dx) ((dx)==-1 ? N.Lb[(dz)+1][(dy)+1] : ((dx)==1 ? N.Rb[(dz)+1][(dy)+1] : N.V[(dz)+1][(dy)+1]))

// ---------------------------- iteration kernel ------------------------------
// One block: 16x16 (z,y) rows x full 192-bit x, halo 8. Computes ge2 (halo 7)
// then the 8 subfield passes with shrinking halo (pass k valid on halo 7-k),
// entirely in LDS. Reads bin (iteration-start state), writes only its core to
// bout (disjoint across blocks -> no races; double-buffered across kernels).
__global__ __launch_bounds__(256) void k_iter(const uint64_t* __restrict__ bin,
                                              uint64_t* __restrict__ bout,
                                              float4* __restrict__ outf,
                                              int zero_pads) {
  __shared__ uint64_t Bt[32 * 32 * 3];
  __shared__ uint64_t Ge[32 * 32 * 3];
  const int tid = threadIdx.x;
  const int bid = blockIdx.x;
  const int n  = bid / 100;
  const int rm = bid - n * 100;
  const int tz = rm / 10, ty = rm - tz * 10;
  const int gz0 = 1 + 16 * tz, gy0 = 1 + 16 * ty;   // both odd

  // Zero bout's pad rows (z or y in {0,161}) once per call (block 0, iter 1).
  if (zero_pads && bid == 0) {
    for (int j = tid; j < 1288; j += 256) {
      int nn, z, y;
      if (j < 648) { nn = j / 324; int r = j - nn * 324;
                     z = (r >= 162) ? 161 : 0; y = (r >= 162) ? r - 162 : r; }
      else { int j2 = j - 648; nn = j2 / 320; int r = j2 - nn * 320;
             y = (r >= 160) ? 161 : 0; z = 1 + ((r >= 160) ? r - 160 : r); }
      uint64_t* p = bout + (((nn * 162 + z) * 162) + y) * 3;
      p[0] = 0; p[1] = 0; p[2] = 0;
    }
  }

  // ---- load tile + halo 8 ----
  for (int ti = tid; ti < 32 * 32 * 3; ti += 256) {
    int lz = ti / 96, rem = ti - lz * 96, ly = rem / 3, w = rem - ly * 3;
    int z = gz0 - 8 + lz, y = gy0 - 8 + ly;
    uint64_t v = 0;
    if ((unsigned)z < 162u && (unsigned)y < 162u)
      v = bin[((n * 162 + z) * 162 + y) * 3 + w];
    Bt[ti] = v;
  }
  __syncthreads();

  // ---- ge2 (C26>=2, i.e. not-endpoint) on halo 7, from iteration-start state
  for (int ti = tid; ti < 30 * 30 * 3; ti += 256) {
    int q = ti / 90, rem = ti - q * 90;
    int lz = 1 + q, ly = 1 + rem / 3, w = rem - (rem / 3) * 3;
    uint64_t res = 0;
    if (Bt[(lz * 32 + ly) * 3 + w] != 0ull) {
      Nbhd N; gather(Bt, lz, ly, w, N);
      uint64_t s = 0, c = 0;
#define ACC(bb) { uint64_t _b = (bb); c |= s & _b; s |= _b; }
#pragma unroll
      for (int dz = -1; dz <= 1; ++dz)
#pragma unroll
        for (int dy = -1; dy <= 1; ++dy) {
          ACC(NB(dz,dy,-1)); ACC(NB(dz,dy,1));
          if (dz != 0 || dy != 0) ACC(NB(dz,dy,0));
        }
#undef ACC
      res = c;
    }
    Ge[(lz * 32 + ly) * 3 + w] = res;
  }
  __syncthreads();

  // ---- 8 subfield passes, halo 7-k, parity per reference offsets order ----
  // offsets (xo,yo,zo) apply to (z,y,x). gz0/gy0 odd => z even <=> lz odd.
  const int PLZ[8] = {1,0,1,0,1,0,1,0};   // lz parity (xo=0 -> z even -> lz odd)
  const int PLY[8] = {1,1,0,0,1,1,0,0};   // ly parity
  for (int k = 0; k < 8; ++k) {
    const int h = 7 - k, cnt1 = 8 + h;
    const uint64_t xmask = (k < 4) ? 0x5555555555555555ull : 0xAAAAAAAAAAAAAAAAull;
    int s0 = 8 - h;
    const int slz = s0 + ((s0 ^ PLZ[k]) & 1);
    const int sly = s0 + ((s0 ^ PLY[k]) & 1);
    for (int ti = tid; ti < cnt1 * cnt1 * 3; ti += 256) {
      int iz = ti / (cnt1 * 3), rem = ti - iz * (cnt1 * 3);
      int iy = rem / 3, w = rem - iy * 3;
      int lz = slz + 2 * iz, ly = sly + 2 * iy;
      uint64_t center = Bt[(lz * 32 + ly) * 3 + w];
      uint64_t active = center & xmask & Ge[(lz * 32 + ly) * 3 + w];
      if (active == 0ull) continue;
      Nbhd N; gather(Bt, lz, ly, w, N);

      // C6 exact 3-bit counter over the 6 faces
      uint64_t on = 0, tw = 0, fo = 0;
#define C6ADD(b) { uint64_t _u = on & (b); on ^= (b); uint64_t _v = tw & _u; tw ^= _u; fo |= _v; }
      C6ADD(NB(-1,0,0)) C6ADD(NB(1,0,0)) C6ADD(NB(0,-1,0))
      C6ADD(NB(0,1,0))  C6ADD(NB(0,0,-1)) C6ADD(NB(0,0,1))
#undef C6ADD
      uint64_t c6eq5 = fo & on & ~tw;
      uint64_t c6le4 = ~(fo & (on | tw));

      // carry-save ==1 detectors over 18 then 26 neighbors
      uint64_t s = 0, c2 = 0;
#define CS(b) { uint64_t _b = (b); c2 |= s & _b; s |= _b; }
      CS(NB(-1,0,0)) CS(NB(1,0,0)) CS(NB(0,-1,0)) CS(NB(0,1,0)) CS(NB(0,0,-1)) CS(NB(0,0,1))
      CS(NB(-1,-1,0)) CS(NB(-1,1,0)) CS(NB(-1,0,-1)) CS(NB(-1,0,1))
      CS(NB(1,-1,0))  CS(NB(1,1,0))  CS(NB(1,0,-1))  CS(NB(1,0,1))
      CS(NB(0,-1,-1)) CS(NB(0,-1,1)) CS(NB(0,1,-1))  CS(NB(0,1,1))
      uint64_t e18 = s & ~c2;
      CS(NB(-1,-1,-1)) CS(NB(-1,-1,1)) CS(NB(-1,1,-1)) CS(NB(-1,1,1))
      CS(NB(1,-1,-1))  CS(NB(1,-1,1))  CS(NB(1,1,-1))  CS(NB(1,1,1))
      uint64_t e26 = s & ~c2;
#undef CS

      // B: corner set with its 6 octant face/edge cells all clear
      uint64_t badB = 0;
#pragma unroll
      for (int sz = -1; sz <= 1; sz += 2)
#pragma unroll
        for (int sy = -1; sy <= 1; sy += 2)
#pragma unroll
          for (int sx = -1; sx <= 1; sx += 2) {
            uint64_t oct = NB(sz,0,0) | NB(0,sy,0) | NB(0,0,sx)
                         | NB(sz,sy,0) | NB(sz,0,sx) | NB(0,sy,sx);
            badB |= NB(sz,sy,sx) & ~oct;
          }
      uint64_t b0ok = ~badB;

      // A: face clear with its full 4-cell in-plane ring set
      uint64_t badA = 0;
      badA |= ~NB(-1,0,0) & NB(-1,-1,0) & NB(-1,1,0) & NB(-1,0,-1) & NB(-1,0,1);
      badA |= ~NB( 1,0,0) & NB( 1,-1,0) & NB( 1,1,0) & NB( 1,0,-1) & NB( 1,0,1);
      badA |= ~NB(0,-1,0) & NB(-1,-1,0) & NB(1,-1,0) & NB(0,-1,-1) & NB(0,-1,1);
      badA |= ~NB(0, 1,0) & NB(-1, 1,0) & NB(1, 1,0) & NB(0, 1,-1) & NB(0, 1,1);
      badA |= ~NB(0,0,-1) & NB(-1,0,-1) & NB(1,0,-1) & NB(0,-1,-1) & NB(0,1,-1);
      badA |= ~NB(0,0, 1) & NB(-1,0, 1) & NB(1,0, 1) & NB(0,-1, 1) & NB(0,1, 1);
      uint64_t a0ok = ~badA;

      uint64_t simple = c6eq5 | e26 | (e18 & b0ok) | (c6le4 & a0ok & b0ok);
      uint64_t del = simple & active;
      if (del) Bt[(lz * 32 + ly) * 3 + w] = center & ~del;
      // concurrent readers only consume non-updated-parity bits of this word;
      // 4B-granular LDS writes can't tear them (same argument as word-level R2)
    }
    __syncthreads();
  }

  // ---- epilogue ----
  if (outf) {
    // final iteration: write float output for core (interior coords)
    for (int ti = tid; ti < 16 * 16 * 40; ti += 256) {
      int iz = ti / 640, rem = ti - iz * 640;
      int iy = rem / 40, g = rem - iy * 40;
      int lz = 8 + iz, ly = 8 + iy;
      const uint64_t* rp = &Bt[(lz * 32 + ly) * 3];
      int bi = 1 + 4 * g;                 // padded x of first of 4
      int wx = bi >> 6, sft = bi & 63;
      uint64_t v = rp[wx] >> sft;
      if (sft > 60) v |= rp[wx + 1] << (64 - sft);
      outf[((n * 160 + (gz0 + iz - 1)) * 160 + (gy0 + iy - 1)) * 40 + g] =
          make_float4((float)(v & 1u), (float)((v >> 1) & 1u),
                      (float)((v >> 2) & 1u), (float)((v >> 3) & 1u));
    }
  } else {
    // write core words back (disjoint across blocks)
    for (int ti = tid; ti < 16 * 16 * 3; ti += 256) {
      int iz = ti / 48, rem = ti - iz * 48, iy = rem / 3, w = rem - iy * 3;
      bout[((n * 162 + gz0 + iz) * 162 + (gy0 + iy)) * 3 + w] =
          Bt[((8 + iz) * 32 + (8 + iy)) * 3 + w];
    }
  }
}

// ---------------------------- launcher --------------------------------------
extern "C" void kernel_launch(void* const* d_in, const int* in_sizes, int n_in,
                              void* d_out, int out_size, void* d_ws, size_t ws_size,
                              hipStream_t stream) {
  const float* in = (const float*)d_in[0];
  float4* out = (float4*)d_out;
  uint64_t* A = (uint64_t*)d_ws;          // bitboard A
  uint64_t* B = A + NW;                   // bitboard B

  dim3 blk(256);
  k_binarize<<<dim3((NW * 64 + 255) / 256), blk, 0, stream>>>(in, A);
  k_iter<<<dim3(200), blk, 0, stream>>>(A, B, nullptr, 1);   // iter 1: A->B (+zero B pads)
  k_iter<<<dim3(200), blk, 0, stream>>>(B, A, nullptr, 0);   // iter 2: B->A
  k_iter<<<dim3(200), blk, 0, stream>>>(A, B, nullptr, 0);   // iter 3: A->B
  k_iter<<<dim3(200), blk, 0, stream>>>(B, A, nullptr, 0);   // iter 4: B->A
  k_iter<<<dim3(200), blk, 0, stream>>>(A, B, out, 0);       // iter 5: A->out
}

// Round 6
// 236.428 us; speedup vs baseline: 3.9598x; 1.1916x over previous
//
#include <hip/hip_runtime.h>
#include <stdint.h>

// No implicit FMA contraction: the JAX eager reference has none across ops;
// where XLA fuses we write fmaf() explicitly.
#pragma clang fp contract(off)

#define PDIM 162
#define WPR  3
#define NW   (2*PDIM*PDIM*WPR)  // 157464 words, 1.26 MB per bitboard
#define OD   160
#define OD2  (160*160)
#define OD3  (160*160*160)
#define NOUT (2*OD3)
#define LSTR 4                  // LDS row stride in u64 (padded from 3)

// ---------------- threefry2x32, JAX partitionable scheme --------------------
__device__ __forceinline__ uint32_t rotl32(uint32_t x, uint32_t r) {
  return (x << r) | (x >> (32u - r));
}

__device__ __forceinline__ uint32_t threefry_bits(uint32_t idx) {
  const uint32_t ks0 = 0u, ks1 = 42u, ks2 = 0x1BD11BDAu ^ 0u ^ 42u;
  uint32_t x0 = 0u + ks0;
  uint32_t x1 = idx + ks1;
#define TFR(r) { x0 += x1; x1 = rotl32(x1, (r)); x1 ^= x0; }
  TFR(13u) TFR(15u) TFR(26u) TFR(6u)
  x0 += ks1; x1 += ks2 + 1u;
  TFR(17u) TFR(29u) TFR(16u) TFR(24u)
  x0 += ks2; x1 += ks0 + 2u;
  TFR(13u) TFR(15u) TFR(26u) TFR(6u)
  x0 += ks0; x1 += ks1 + 3u;
  TFR(17u) TFR(29u) TFR(16u) TFR(24u)
  x0 += ks1; x1 += ks2 + 4u;
  TFR(13u) TFR(15u) TFR(26u) TFR(6u)
  x0 += ks2; x1 += ks0 + 5u;
#undef TFR
  return x0 ^ x1;
}

// ------------- XLA-CPU (Cephes) float32 log replication ---------------------
__device__ __forceinline__ float xla_logf(float xin) {
  uint32_t bits = __float_as_uint(xin);
  float e = (float)((int)(bits >> 23) - 126);
  float x = __uint_as_float((bits & 0x007fffffu) | 0x3f000000u);
  const float SQRTHF = 0.707106781186547524f;
  bool lt = (x < SQRTHF);
  float tmp = lt ? x : 0.0f;
  e = e - (lt ? 1.0f : 0.0f);
  x = x - 1.0f;
  x = x + tmp;
  float z = x * x;
  float y = 7.0376836292e-2f;
  y = fmaf(y, x, -1.1514610310e-1f);
  y = fmaf(y, x,  1.1676998740e-1f);
  y = fmaf(y, x, -1.2420140846e-1f);
  y = fmaf(y, x,  1.4249322787e-1f);
  y = fmaf(y, x, -1.6668057665e-1f);
  y = fmaf(y, x,  2.0000714765e-1f);
  y = fmaf(y, x, -2.4999993993e-1f);
  y = fmaf(y, x,  3.3333331174e-1f);
  y = y * x;
  y = y * z;
  y = fmaf(e, -2.12194440e-4f, y);
  y = fmaf(-0.5f, z, y);
  x = x + y;
  x = fmaf(e, 0.693359375f, x);
  return x;
}

__device__ __forceinline__ float xla_log1pf(float x) {
  float for_large = xla_logf(x + 1.0f);
  float for_small = fmaf(-0.5f, x, 1.0f) * x;
  return (fabsf(x) < 1e-4f) ? for_small : for_large;
}

// ---------------------------- binarize --------------------------------------
__global__ __launch_bounds__(256) void k_binarize(const float* __restrict__ in,
                                                  uint64_t* __restrict__ bits) {
  uint32_t t = blockIdx.x * 256u + threadIdx.x;
  uint32_t w = t >> 6, lane = t & 63u;
  if (w >= (uint32_t)NW) return;          // wave-uniform
  uint32_t row = w / 3u, wx = w - row * 3u;
  uint32_t n  = row / (uint32_t)(PDIM * PDIM);
  uint32_t rr = row - n * (uint32_t)(PDIM * PDIM);
  uint32_t z  = rr / (uint32_t)PDIM;
  uint32_t y  = rr - z * (uint32_t)PDIM;
  uint32_t x  = wx * 64u + lane;
  bool pred = false;
  // pad voxels are provably 0: |0.33*noise| <= 6.08 < 18.42 = |log alpha(0)|
  if ((z - 1u) < 160u && (y - 1u) < 160u && (x - 1u) < 160u) {
    float v = in[((n * 160u + (z - 1u)) * 160u + (y - 1u)) * 160u + (x - 1u)];
    uint32_t i = row * 162u + x;          // flat padded index for RNG
    uint32_t b = threefry_bits(i);
    float f  = __uint_as_float((b >> 9) | 0x3f800000u) - 1.0f;
    float uu = fmaxf(1e-8f, f + 1e-8f);
    float la = xla_logf((v + 1e-8f) / ((1.0f - v) + 1e-8f));
    float noise = xla_logf(uu) - xla_log1pf(-uu);
    float zs = la + noise * 0.33f;
    pred = (zs > 1.1920928955078125e-7f); // logistic>0.5 iff z>2^-23
  }
  uint64_t m = __ballot(pred);
  if (lane == 0) bits[w] = m;
}

// ------------------------ neighborhood gather (LDS) -------------------------
struct Nbhd { uint64_t V[3][3], Lb[3][3], Rb[3][3]; };

__device__ __forceinline__ void gather(const uint64_t* __restrict__ Bt,
                                       int lz, int ly, int w, Nbhd& N) {
#pragma unroll
  for (int dz = -1; dz <= 1; ++dz)
#pragma unroll
    for (int dy = -1; dy <= 1; ++dy) {
      const uint64_t* rp = &Bt[((lz + dz) * 32 + (ly + dy)) * LSTR];
      uint64_t r0 = rp[0], r1 = rp[1], r2 = rp[2];
      uint64_t b = (w == 0) ? r0 : ((w == 1) ? r1 : r2);
      uint64_t a = (w == 0) ? 0ull : ((w == 1) ? r0 : r1);
      uint64_t d = (w == 0) ? r1 : ((w == 1) ? r2 : 0ull);
      N.V [dz+1][dy+1] = b;
      N.Lb[dz+1][dy+1] = (b << 1) | (a >> 63);
      N.Rb[dz+1][dy+1] = (b >> 1) | (d << 63);
    }
}

#define NB(dz,dy,dx) ((dx)==-1 ? N.Lb[(dz)+1][(dy)+1] : ((dx)==1 ? N.Rb[(dz)+1][(dy)+1] : N.V[(dz)+1][(dy)+1]))

// ---------------------------- iteration kernel ------------------------------
// One block: 16x16 (z,y) core x full 192-bit x, halo 8 -> 32x32 LDS tile.
// ge2 on halo 7, then 8 subfield passes with shrinking halo; writes core only.
__global__ __launch_bounds__(1024) void k_iter(const uint64_t* __restrict__ bin,
                                               uint64_t* __restrict__ bout,
                                               int zero_pads) {
  __shared__ uint64_t Bt[32 * 32 * LSTR];
  __shared__ uint64_t Ge[32 * 32 * LSTR];
  const int tid = threadIdx.x;
  const int bid = blockIdx.x;
  const int n  = bid / 100;
  const int rm = bid - n * 100;
  const int tz = rm / 10, ty = rm - tz * 10;
  const int gz0 = 1 + 16 * tz, gy0 = 1 + 16 * ty;   // both odd

  // Zero bout's pad rows (z or y in {0,161}) once per call (block 0, iter 1).
  if (zero_pads && bid == 0) {
    for (int j = tid; j < 1288; j += 1024) {
      int nn, z, y;
      if (j < 648) { nn = j / 324; int r = j - nn * 324;
                     z = (r >= 162) ? 161 : 0; y = (r >= 162) ? r - 162 : r; }
      else { int j2 = j - 648; nn = j2 / 320; int r = j2 - nn * 320;
             y = (r >= 160) ? 161 : 0; z = 1 + ((r >= 160) ? r - 160 : r); }
      uint64_t* p = bout + (((nn * 162 + z) * 162) + y) * 3;
      p[0] = 0; p[1] = 0; p[2] = 0;
    }
  }

  // ---- load tile + halo 8 ----
  for (int ti = tid; ti < 32 * 32 * 3; ti += 1024) {
    int lz = ti / 96, rem = ti - lz * 96, ly = rem / 3, w = rem - ly * 3;
    int z = gz0 - 8 + lz, y = gy0 - 8 + ly;
    uint64_t v = 0;
    if ((unsigned)z < 162u && (unsigned)y < 162u)
      v = bin[((n * 162 + z) * 162 + y) * 3 + w];
    Bt[(lz * 32 + ly) * LSTR + w] = v;
  }
  __syncthreads();

  // ---- ge2 (C26>=2, i.e. not-endpoint) on halo 7, from iteration-start state
  for (int ti = tid; ti < 30 * 30 * 3; ti += 1024) {
    int q = ti / 90, rem = ti - q * 90;
    int lz = 1 + q, ly = 1 + rem / 3, w = rem - (rem / 3) * 3;
    uint64_t res = 0;
    if (Bt[(lz * 32 + ly) * LSTR + w] != 0ull) {
      Nbhd N; gather(Bt, lz, ly, w, N);
      uint64_t s = 0, c = 0;
#define ACC(bb) { uint64_t _b = (bb); c |= s & _b; s |= _b; }
#pragma unroll
      for (int dz = -1; dz <= 1; ++dz)
#pragma unroll
        for (int dy = -1; dy <= 1; ++dy) {
          ACC(NB(dz,dy,-1)); ACC(NB(dz,dy,1));
          if (dz != 0 || dy != 0) ACC(NB(dz,dy,0));
        }
#undef ACC
      res = c;
    }
    Ge[(lz * 32 + ly) * LSTR + w] = res;
  }
  __syncthreads();

  // ---- 8 subfield passes, halo 7-k, parity per reference offsets order ----
  const int PLZ[8] = {1,0,1,0,1,0,1,0};   // lz parity (xo=0 -> z even -> lz odd)
  const int PLY[8] = {1,1,0,0,1,1,0,0};   // ly parity
  for (int k = 0; k < 8; ++k) {
    const int h = 7 - k, cnt1 = 8 + h;
    const uint64_t xmask = (k < 4) ? 0x5555555555555555ull : 0xAAAAAAAAAAAAAAAAull;
    int s0 = 8 - h;
    const int slz = s0 + ((s0 ^ PLZ[k]) & 1);
    const int sly = s0 + ((s0 ^ PLY[k]) & 1);
    for (int ti = tid; ti < cnt1 * cnt1 * 3; ti += 1024) {
      int iz = ti / (cnt1 * 3), rem = ti - iz * (cnt1 * 3);
      int iy = rem / 3, w = rem - iy * 3;
      int lz = slz + 2 * iz, ly = sly + 2 * iy;
      uint64_t center = Bt[(lz * 32 + ly) * LSTR + w];
      uint64_t active = center & xmask & Ge[(lz * 32 + ly) * LSTR + w];
      if (active == 0ull) continue;
      Nbhd N; gather(Bt, lz, ly, w, N);

      // C6 exact 3-bit counter over the 6 faces
      uint64_t on = 0, tw = 0, fo = 0;
#define C6ADD(b) { uint64_t _u = on & (b); on ^= (b); uint64_t _v = tw & _u; tw ^= _u; fo |= _v; }
      C6ADD(NB(-1,0,0)) C6ADD(NB(1,0,0)) C6ADD(NB(0,-1,0))
      C6ADD(NB(0,1,0))  C6ADD(NB(0,0,-1)) C6ADD(NB(0,0,1))
#undef C6ADD
      uint64_t c6eq5 = fo & on & ~tw;
      uint64_t c6le4 = ~(fo & (on | tw));

      // carry-save ==1 detectors over 18 then 26 neighbors
      uint64_t s = 0, c2 = 0;
#define CS(b) { uint64_t _b = (b); c2 |= s & _b; s |= _b; }
      CS(NB(-1,0,0)) CS(NB(1,0,0)) CS(NB(0,-1,0)) CS(NB(0,1,0)) CS(NB(0,0,-1)) CS(NB(0,0,1))
      CS(NB(-1,-1,0)) CS(NB(-1,1,0)) CS(NB(-1,0,-1)) CS(NB(-1,0,1))
      CS(NB(1,-1,0))  CS(NB(1,1,0))  CS(NB(1,0,-1))  CS(NB(1,0,1))
      CS(NB(0,-1,-1)) CS(NB(0,-1,1)) CS(NB(0,1,-1))  CS(NB(0,1,1))
      uint64_t e18 = s & ~c2;
      CS(NB(-1,-1,-1)) CS(NB(-1,-1,1)) CS(NB(-1,1,-1)) CS(NB(-1,1,1))
      CS(NB(1,-1,-1))  CS(NB(1,-1,1))  CS(NB(1,1,-1))  CS(NB(1,1,1))
      uint64_t e26 = s & ~c2;
#undef CS

      // B: corner set with its 6 octant face/edge cells all clear
      uint64_t badB = 0;
#pragma unroll
      for (int sz = -1; sz <= 1; sz += 2)
#pragma unroll
        for (int sy = -1; sy <= 1; sy += 2)
#pragma unroll
          for (int sx = -1; sx <= 1; sx += 2) {
            uint64_t oct = NB(sz,0,0) | NB(0,sy,0) | NB(0,0,sx)
                         | NB(sz,sy,0) | NB(sz,0,sx) | NB(0,sy,sx);
            badB |= NB(sz,sy,sx) & ~oct;
          }
      uint64_t b0ok = ~badB;

      // A: face clear with its full 4-cell in-plane ring set
      uint64_t badA = 0;
      badA |= ~NB(-1,0,0) & NB(-1,-1,0) & NB(-1,1,0) & NB(-1,0,-1) & NB(-1,0,1);
      badA |= ~NB( 1,0,0) & NB( 1,-1,0) & NB( 1,1,0) & NB( 1,0,-1) & NB( 1,0,1);
      badA |= ~NB(0,-1,0) & NB(-1,-1,0) & NB(1,-1,0) & NB(0,-1,-1) & NB(0,-1,1);
      badA |= ~NB(0, 1,0) & NB(-1, 1,0) & NB(1, 1,0) & NB(0, 1,-1) & NB(0, 1,1);
      badA |= ~NB(0,0,-1) & NB(-1,0,-1) & NB(1,0,-1) & NB(0,-1,-1) & NB(0,1,-1);
      badA |= ~NB(0,0, 1) & NB(-1,0, 1) & NB(1,0, 1) & NB(0,-1, 1) & NB(0,1, 1);
      uint64_t a0ok = ~badA;

      uint64_t simple = c6eq5 | e26 | (e18 & b0ok) | (c6le4 & a0ok & b0ok);
      uint64_t del = simple & active;
      if (del) Bt[(lz * 32 + ly) * LSTR + w] = center & ~del;
      // readers only consume non-updated-parity bits; tearing-safe (R5 arg)
    }
    __syncthreads();
  }

  // ---- write core words back (disjoint across blocks) ----
  for (int ti = tid; ti < 16 * 16 * 3; ti += 1024) {
    int iz = ti / 48, rem = ti - iz * 48, iy = rem / 3, w = rem - iy * 3;
    bout[((n * 162 + gz0 + iz) * 162 + (gy0 + iy)) * 3 + w] =
        Bt[((8 + iz) * 32 + (8 + iy)) * LSTR + w];
  }
}

// ---------------------------- output ----------------------------------------
__global__ __launch_bounds__(256) void k_output(const uint64_t* __restrict__ bits,
                                                float4* __restrict__ out) {
  uint32_t t = blockIdx.x * 256u + threadIdx.x;
  if (t >= (uint32_t)(NOUT / 4)) return;
  uint32_t i = t * 4u;
  uint32_t n = i / (uint32_t)OD3;
  uint32_t r = i - n * (uint32_t)OD3;
  uint32_t z = r / (uint32_t)OD2; r -= z * (uint32_t)OD2;
  uint32_t y = r / (uint32_t)OD;
  uint32_t x = r - y * (uint32_t)OD;
  uint32_t row = (n * 162u + z + 1u) * 162u + (y + 1u);
  uint32_t bi = x + 1u;
  uint32_t wx = bi >> 6, sft = bi & 63u;
  uint64_t v = bits[row * 3u + wx] >> sft;
  if (sft > 60u) v |= bits[row * 3u + wx + 1u] << (64u - sft);
  out[t] = make_float4((float)(v & 1u), (float)((v >> 1) & 1u),
                       (float)((v >> 2) & 1u), (float)((v >> 3) & 1u));
}

// ---------------------------- launcher --------------------------------------
extern "C" void kernel_launch(void* const* d_in, const int* in_sizes, int n_in,
                              void* d_out, int out_size, void* d_ws, size_t ws_size,
                              hipStream_t stream) {
  const float* in = (const float*)d_in[0];
  float4* out = (float4*)d_out;
  uint64_t* A = (uint64_t*)d_ws;          // bitboard A
  uint64_t* B = A + NW;                   // bitboard B

  k_binarize<<<dim3((NW * 64 + 255) / 256), dim3(256), 0, stream>>>(in, A);
  k_iter<<<dim3(200), dim3(1024), 0, stream>>>(A, B, 1);  // iter 1 (+zero B pads)
  k_iter<<<dim3(200), dim3(1024), 0, stream>>>(B, A, 0);  // iter 2
  k_iter<<<dim3(200), dim3(1024), 0, stream>>>(A, B, 0);  // iter 3
  k_iter<<<dim3(200), dim3(1024), 0, stream>>>(B, A, 0);  // iter 4
  k_iter<<<dim3(200), dim3(1024), 0, stream>>>(A, B, 0);  // iter 5
  k_output<<<dim3((NOUT / 4 + 255) / 256), dim3(256), 0, stream>>>(B, out);
}